// Round 11
// baseline (20.943 us; speedup 1.0000x reference)
//
#include <hip/hip_runtime.h>

typedef float f32x2 __attribute__((ext_vector_type(2)));
typedef float f32x4 __attribute__((ext_vector_type(4)));

constexpr int N    = 8192;
constexpr int BLK  = 256;
constexpr int BX   = 128;      // x-points per block
constexpr int BY   = 2048;     // y-points per block (one y-range)
constexpr int NYR  = N / BY;   // 4 y-ranges
constexpr int P    = 8;        // x-points per thread
constexpr int NSL  = 16;       // y-slices per block
constexpr int SY   = BY / NSL; // 128 y per slice (64 packed pairs)
constexpr int SPAD = SY + 1;   // 129 f32x4 per slice: +4 banks per slice
constexpr int RPAD = BX + 4;   // 132: +4 banks per slice row

// grid 512: dir = b>>8, xbk = (b>>2)&63, yr = b&3.
// y staged pair-packed SoA: pair p -> {x0,x1,y0,y1},{z0,z1,w0,w1} so the
// 2-eval inner body is 3 v_pk_fma_f32 + 2 v_min_f32 (was 6 fma + min3).
// NOTE: f32x4{..} braced-init, NOT (f32x4)(..) — the latter is the C++
// comma operator + splat-cast (Round-10 bug: staged tiles were splat(b1)).
__global__ __launch_bounds__(BLK) void chamfer_stage1(
    const float* __restrict__ pred, const float* __restrict__ label,
    float* __restrict__ minbuf)
{
    int b   = blockIdx.x;
    int dir = b >> 8;
    int xbk = (b >> 2) & 63;
    int yr  = b & 3;

    const float* A = dir ? label : pred;   // query set
    const float* B = dir ? pred  : label;  // target set

    __shared__ f32x4 sy[NSL * SPAD];       // 33 KB
    __shared__ float red[NSL * RPAD];      // 8.4 KB

    int u  = threadIdx.x & 15;
    int ys = threadIdx.x >> 4;

    f32x2 cxa[P], cxb[P], cxc[P];
    float xn[P];
    f32x2 m[P];
    #pragma unroll
    for (int k = 0; k < P; ++k) {
        int idx = xbk * BX + k * 16 + u;
        float a = A[3*idx], c = A[3*idx+1], d = A[3*idx+2];
        cxa[k] = f32x2{-2.f * a, -2.f * a};
        cxb[k] = f32x2{-2.f * c, -2.f * c};
        cxc[k] = f32x2{-2.f * d, -2.f * d};
        xn[k] = a*a + c*c + d*d;
        m[k]  = f32x2{3.4e38f, 3.4e38f};
    }

    // stage y-range as packed pairs (+norms in second word)
    for (int i = threadIdx.x; i < BY / 2; i += BLK) {
        int g0 = yr * BY + 2 * i;
        float a0 = B[3*g0+0], b0 = B[3*g0+1], c0 = B[3*g0+2];
        float a1 = B[3*g0+3], b1 = B[3*g0+4], c1 = B[3*g0+5];
        int slice = i >> 6;            // 64 pairs per slice
        int pair  = i & 63;
        int base  = slice * SPAD + 2 * pair;
        sy[base]     = f32x4{a0, a1, b0, b1};
        sy[base + 1] = f32x4{c0, c1,
                             a0*a0 + b0*b0 + c0*c0,
                             a1*a1 + b1*b1 + c1*c1};
    }
    __syncthreads();

    const f32x4* s = &sy[ys * SPAD];
    #pragma unroll 4
    for (int j = 0; j < SY / 2; ++j) {
        f32x4 pa = s[2*j], pb = s[2*j + 1];   // {x01,y01}, {z01,w01}
        #pragma unroll
        for (int k = 0; k < P; ++k) {
            f32x2 t = cxa[k] * pa.xy + (cxb[k] * pa.zw +
                      (cxc[k] * pb.xy + pb.zw));       // 3 v_pk_fma_f32
            m[k].x = fminf(m[k].x, t.x);
            m[k].y = fminf(m[k].y, t.y);
        }
    }

    #pragma unroll
    for (int k = 0; k < P; ++k) {
        float mm = fminf(m[k].x, m[k].y);
        red[ys * RPAD + k * 16 + u] = fmaxf(mm + xn[k], 0.f);
    }
    __syncthreads();

    if (threadIdx.x < BX) {
        float v = red[threadIdx.x];
        #pragma unroll
        for (int q = 1; q < NSL; ++q)
            v = fminf(v, red[q * RPAD + threadIdx.x]);
        minbuf[yr * (2 * N) + dir * N + xbk * BX + threadIdx.x] = v;
    }
}

// 16 blocks x 256 threads: column float4 min over 4 ranges, sqrt, block sum.
__global__ __launch_bounds__(256) void chamfer_stage2(
    const float4* __restrict__ minbuf4, float* __restrict__ bsum)
{
    int g = blockIdx.x * 256 + threadIdx.x;   // float4 index in [0, 4096)
    float4 v = minbuf4[g];
    #pragma unroll
    for (int r = 1; r < NYR; ++r) {
        float4 w = minbuf4[r * 4096 + g];
        v.x = fminf(v.x, w.x); v.y = fminf(v.y, w.y);
        v.z = fminf(v.z, w.z); v.w = fminf(v.w, w.w);
    }
    float s = sqrtf(v.x) + sqrtf(v.y) + sqrtf(v.z) + sqrtf(v.w);
    for (int off = 32; off; off >>= 1) s += __shfl_down(s, off);
    __shared__ float r2[4];
    if ((threadIdx.x & 63) == 0) r2[threadIdx.x >> 6] = s;
    __syncthreads();
    if (threadIdx.x == 0)
        bsum[blockIdx.x] = r2[0] + r2[1] + r2[2] + r2[3];
}

// one wave: final fixed-order sum of 16 block partials, scale by 1/N.
__global__ __launch_bounds__(64) void chamfer_stage3(
    const float* __restrict__ bsum, float* __restrict__ out)
{
    float s = (threadIdx.x < 16) ? bsum[threadIdx.x] : 0.f;
    for (int off = 32; off; off >>= 1) s += __shfl_down(s, off);
    if (threadIdx.x == 0) out[0] = s * (1.0f / N);   // mean_x(min)+mean_y(min)
}

extern "C" void kernel_launch(void* const* d_in, const int* in_sizes, int n_in,
                              void* d_out, int out_size, void* d_ws, size_t ws_size,
                              hipStream_t stream) {
    const float* pred  = (const float*)d_in[0];
    const float* label = (const float*)d_in[1];
    float* out    = (float*)d_out;
    float* minbuf = (float*)d_ws;                 // NYR*2N floats = 256 KB
    float* bsum   = minbuf + NYR * 2 * N;         // 16 floats

    chamfer_stage1<<<dim3(2 * (N / BX) * NYR), dim3(BLK), 0, stream>>>(pred, label, minbuf);
    chamfer_stage2<<<dim3(16), dim3(256), 0, stream>>>((const float4*)minbuf, bsum);
    chamfer_stage3<<<dim3(1), dim3(64), 0, stream>>>(bsum, out);
}